// Round 7
// baseline (323.943 us; speedup 1.0000x reference)
//
#include <hip/hip_runtime.h>

#define B_ 32
#define K_ 1024
#define F_ 128
#define E_ 128
#define OUT2_ 125
#define ALPHA_ 0.2f

typedef __bf16 bf16x8_t __attribute__((ext_vector_type(8)));
typedef float  f32x4_t  __attribute__((ext_vector_type(4)));

// ------- x transpose+cvt + scores + (fused) prep ----------------------------
__global__ __launch_bounds__(256) void k_xts(const float* __restrict__ x,
                                             const float* __restrict__ lin_w,
                                             const float* __restrict__ lin_b,
                                             const float* __restrict__ a,
                                             unsigned short* __restrict__ xt,
                                             float* __restrict__ s1,
                                             float* __restrict__ s2) {
    int kt = blockIdx.x;
    int b  = blockIdx.y;
    int t  = threadIdx.x;
    __shared__ float xs[64 * 132];
    __shared__ float red1[4][64], red2[4][64];
    __shared__ float wsl[260];

    // ws: waves 0-1 -> a1 path (f = t), waves 2-3 -> a2 path
    {
        int f = t & 127, sel = t >> 7;
        const float* av = a + sel * 128;
        float acc = 0.f;
#pragma unroll 8
        for (int e = 0; e < E_; ++e) acc += lin_w[e * F_ + f] * av[e];
        wsl[sel * 128 + f] = acc;
        if (t < 2) {
            const float* aw = a + t * 128;
            float c = 0.f;
#pragma unroll 8
            for (int e = 0; e < E_; ++e) c += lin_b[e] * aw[e];
            wsl[256 + t] = c;
        }
    }
    const float* xb = x + ((size_t)b * K_ + kt * 64) * F_;
#pragma unroll
    for (int q = 0; q < 8; ++q) {
        int flat = q * 256 + t;
        int kk = flat >> 5, f4 = flat & 31;
        float4 v = *(const float4*)(xb + (size_t)kk * F_ + f4 * 4);
        xs[kk * 132 + f4 * 4]     = v.x;
        xs[kk * 132 + f4 * 4 + 1] = v.y;
        xs[kk * 132 + f4 * 4 + 2] = v.z;
        xs[kk * 132 + f4 * 4 + 3] = v.w;
    }
    __syncthreads();
    // transpose-pack (bf16) — native casts
    {
        int f = t >> 1, half = t & 1;
        union { __bf16 h[32]; uint4 v[4]; } pack;
#pragma unroll
        for (int i = 0; i < 32; ++i) pack.h[i] = (__bf16)xs[(half * 32 + i) * 132 + f];
        unsigned short* dst = xt + (((size_t)(b * 16 + kt) * 128 + f) * 64 + half * 32);
        uint4* d4 = (uint4*)dst;
#pragma unroll
        for (int i = 0; i < 4; ++i) d4[i] = pack.v[i];
    }
    // scores: row r = t&63, f-segment p = t>>6 (32 f each), reduce via LDS
    {
        int r = t & 63, p = t >> 6;
        const float4* xr = (const float4*)&xs[r * 132 + p * 32];
        const float4* w1 = (const float4*)&wsl[p * 32];
        const float4* w2 = (const float4*)&wsl[128 + p * 32];
        float a1 = 0.f, a2 = 0.f;
#pragma unroll
        for (int q = 0; q < 8; ++q) {
            float4 xv = xr[q];
            float4 wa = w1[q], wb = w2[q];
            a1 += xv.x * wa.x + xv.y * wa.y + xv.z * wa.z + xv.w * wa.w;
            a2 += xv.x * wb.x + xv.y * wb.y + xv.z * wb.z + xv.w * wb.w;
        }
        red1[p][r] = a1; red2[p][r] = a2;
    }
    __syncthreads();
    if (t < 64) {
        s1[(size_t)b * K_ + kt * 64 + t] =
            red1[0][t] + red1[1][t] + red1[2][t] + red1[3][t] + wsl[256];
    } else if (t < 128) {
        int r = t - 64;
        s2[(size_t)b * K_ + kt * 64 + r] =
            red2[0][r] + red2[1][r] + red2[2][r] + red2[3][r] + wsl[257];
    }
}

// -------- fused softmax + att@x: phase-0 burst softmax, then MFMA loop -------
// Each block owns att rows [i0,i0+32) of batch b.
//  phase 0: two-pass softmax (sum, then normalize) over the 32 rows; att
//           written as ONE coalesced burst BEFORE any loop barrier (round-1
//           lesson: in-loop stores serialize on the per-barrier vmcnt drain;
//           a single pre-loop burst behaves like the standalone k_softmax).
//  loop:    round-6 structure — A fragments read back from att (now
//           guaranteed local-XCD-L2-hot: this block just wrote them; no L1
//           staleness since these lines were never read before the barrier),
//           X double-buffered in LDS, XOR swizzle, A register-pipelined.
//  XCD-chunked swizzle (1024%8==0, bijective): each XCD owns 4 b values, so
//  its xt working set (4 x 1MB) exactly fills the 4MB per-XCD L2.
__global__ __launch_bounds__(256, 4) void k_attx(const float* __restrict__ s1,
                                                 const float* __restrict__ s2,
                                                 const float* __restrict__ bias,
                                                 const unsigned short* __restrict__ xt,
                                                 const float* __restrict__ x,
                                                 float* __restrict__ att,
                                                 unsigned short* __restrict__ ht) {
    int flat = blockIdx.y * gridDim.x + blockIdx.x;      // [0,1024)
    int swz  = (flat & 7) * 128 + (flat >> 3);           // XCD-chunked, bijective
    int b  = swz >> 5;
    int i0 = (swz & 31) * 32;
    int t  = threadIdx.x;
    int wave = t >> 6, lane = t & 63;
    int quad = lane >> 4, l15 = lane & 15;

    __shared__ unsigned short X_s[2][128 * 64];   // swizzled, double-buffered

    // ---- phase 0: softmax rows [i0,i0+32), 8 threads/row, 128 k each ----
    {
        int ai = t >> 3, aq = t & 7;
        float sv = s1[b * K_ + i0 + ai];
        const float4* s2p = (const float4*)(s2 + (size_t)b * K_ + aq * 128);
        const float4* bp  = (const float4*)(bias + (size_t)(i0 + ai) * K_ + aq * 128);
        float sum = 0.f;
#pragma unroll 8
        for (int c = 0; c < 32; ++c) {
            float4 s2v = s2p[c], bv = bp[c];
            float v;
            v = sv + s2v.x; v = v > 0.f ? v : ALPHA_ * v; sum += __expf(v + bv.x);
            v = sv + s2v.y; v = v > 0.f ? v : ALPHA_ * v; sum += __expf(v + bv.y);
            v = sv + s2v.z; v = v > 0.f ? v : ALPHA_ * v; sum += __expf(v + bv.z);
            v = sv + s2v.w; v = v > 0.f ? v : ALPHA_ * v; sum += __expf(v + bv.w);
        }
        sum += __shfl_xor(sum, 1, 64);
        sum += __shfl_xor(sum, 2, 64);
        sum += __shfl_xor(sum, 4, 64);
        float rv = 1.f / sum;
        float4* ap = (float4*)(att + ((size_t)(b * K_ + i0 + ai)) * K_ + aq * 128);
#pragma unroll 8
        for (int c = 0; c < 32; ++c) {
            float4 s2v = s2p[c], bv = bp[c];
            float4 o; float v;
            v = sv + s2v.x; v = v > 0.f ? v : ALPHA_ * v; o.x = __expf(v + bv.x) * rv;
            v = sv + s2v.y; v = v > 0.f ? v : ALPHA_ * v; o.y = __expf(v + bv.y) * rv;
            v = sv + s2v.z; v = v > 0.f ? v : ALPHA_ * v; o.z = __expf(v + bv.z) * rv;
            v = sv + s2v.w; v = v > 0.f ? v : ALPHA_ * v; o.w = __expf(v + bv.w) * rv;
            ap[c] = o;
        }
    }
    __syncthreads();   // vmcnt drain + barrier: att rows visible block-wide

    const float* ab  = att + ((size_t)b * K_ + i0) * K_;
    const uint4* xtb = (const uint4*)(xt + (size_t)b * 16 * 128 * 64);

    const float* arow[2];
    arow[0] = ab + (size_t)l15 * K_ + quad * 8;
    arow[1] = arow[0] + 16 * K_;

    f32x4_t acc[2][2];
#pragma unroll
    for (int m = 0; m < 2; ++m)
#pragma unroll
        for (int n = 0; n < 2; ++n) acc[m][n] = (f32x4_t)(0.f);

    bf16x8_t afc[2][2];
    // prologue: issue A0 loads, stage X0 into buf 0, cvt A0
    {
        float4 av[2][2][2];
#pragma unroll
        for (int m = 0; m < 2; ++m)
#pragma unroll
            for (int kh = 0; kh < 2; ++kh) {
                av[m][kh][0] = *(const float4*)(arow[m] + kh * 32);
                av[m][kh][1] = *(const float4*)(arow[m] + kh * 32 + 4);
            }
#pragma unroll
        for (int q = 0; q < 4; ++q) {
            int flat2 = q * 256 + t;
            int row = flat2 >> 3, g = flat2 & 7;
            *(uint4*)&X_s[0][row * 64 + 8 * (g ^ (row & 7))] = xtb[flat2];
        }
#pragma unroll
        for (int m = 0; m < 2; ++m)
#pragma unroll
            for (int kh = 0; kh < 2; ++kh) {
                union { __bf16 h[8]; bf16x8_t v; } p;
                float4 v0 = av[m][kh][0], v1 = av[m][kh][1];
                p.h[0] = (__bf16)v0.x; p.h[1] = (__bf16)v0.y;
                p.h[2] = (__bf16)v0.z; p.h[3] = (__bf16)v0.w;
                p.h[4] = (__bf16)v1.x; p.h[5] = (__bf16)v1.y;
                p.h[6] = (__bf16)v1.z; p.h[7] = (__bf16)v1.w;
                afc[m][kh] = p.v;
            }
    }
    __syncthreads();

    int cur = 0;
#pragma unroll
    for (int kt = 0; kt < 16; ++kt) {
        uint4 xn[4];
        float4 av[2][2][2];
        if (kt < 15) {
            // issue next X + next A loads (consumed after the MFMAs below)
            const uint4* src = xtb + (size_t)(kt + 1) * 1024;
#pragma unroll
            for (int q = 0; q < 4; ++q) xn[q] = src[q * 256 + t];
            int ko = (kt + 1) * 64;
#pragma unroll
            for (int m = 0; m < 2; ++m)
#pragma unroll
                for (int kh = 0; kh < 2; ++kh) {
                    av[m][kh][0] = *(const float4*)(arow[m] + ko + kh * 32);
                    av[m][kh][1] = *(const float4*)(arow[m] + ko + kh * 32 + 4);
                }
        }
        // MFMAs for tile kt from afc + X_s[cur]
#pragma unroll
        for (int kh = 0; kh < 2; ++kh) {
            bf16x8_t bff[2];
#pragma unroll
            for (int n = 0; n < 2; ++n) {
                int row = wave * 32 + n * 16 + l15;
                bff[n] = *(const bf16x8_t*)&X_s[cur][row * 64 + 8 * (((kh << 2) | quad) ^ (row & 7))];
            }
#pragma unroll
            for (int m = 0; m < 2; ++m)
#pragma unroll
                for (int n = 0; n < 2; ++n)
                    acc[m][n] = __builtin_amdgcn_mfma_f32_16x16x32_bf16(afc[m][kh], bff[n], acc[m][n], 0, 0, 0);
        }
        if (kt < 15) {
            // cvt next A into afc (after MFMA issue — latency hidden)
#pragma unroll
            for (int m = 0; m < 2; ++m)
#pragma unroll
                for (int kh = 0; kh < 2; ++kh) {
                    union { __bf16 h[8]; bf16x8_t v; } p;
                    float4 v0 = av[m][kh][0], v1 = av[m][kh][1];
                    p.h[0] = (__bf16)v0.x; p.h[1] = (__bf16)v0.y;
                    p.h[2] = (__bf16)v0.z; p.h[3] = (__bf16)v0.w;
                    p.h[4] = (__bf16)v1.x; p.h[5] = (__bf16)v1.y;
                    p.h[6] = (__bf16)v1.z; p.h[7] = (__bf16)v1.w;
                    afc[m][kh] = p.v;
                }
            // stage next X into buf[cur^1]
#pragma unroll
            for (int q = 0; q < 4; ++q) {
                int flat2 = q * 256 + t;
                int row = flat2 >> 3, g = flat2 & 7;
                *(uint4*)&X_s[cur ^ 1][row * 64 + 8 * (g ^ (row & 7))] = xn[q];
            }
        }
        __syncthreads();
        cur ^= 1;
    }
    // epilogue: ht[b][f][i] = bf16(acc + x residual), 8B packed along i
#pragma unroll
    for (int m = 0; m < 2; ++m) {
#pragma unroll
        for (int n = 0; n < 2; ++n) {
            int f = wave * 32 + n * 16 + l15;
            int ib = i0 + m * 16 + quad * 4;
            union { __bf16 h[4]; ushort4 v; } p;
#pragma unroll
            for (int r = 0; r < 4; ++r) {
                int i = ib + r;
                p.h[r] = (__bf16)(acc[m][n][r] + x[((size_t)b * K_ + i) * F_ + f]);
            }
            *(ushort4*)&ht[((size_t)b * F_ + f) * K_ + ib] = p.v;
        }
    }
}

// ---------------- out2 MFMA split-K: per (fh,b,ks): C[o128][f64], K=256 ------
__global__ __launch_bounds__(256) void k_out2m(const unsigned short* __restrict__ ht,
                                               const float* __restrict__ w2,
                                               float* __restrict__ part) {
    int b  = blockIdx.y;
    int f0 = blockIdx.x * 64;
    int ks = blockIdx.z;
    int t  = threadIdx.x;
    int wave = t >> 6, lane = t & 63;
    int quad = lane >> 4, l15 = lane & 15;

    __shared__ unsigned short W_s[128 * 72];   // 128o x 64k
    __shared__ unsigned short H_s[64 * 72];    // 64f  x 64k

    f32x4_t acc[8];
#pragma unroll
    for (int m = 0; m < 8; ++m) acc[m] = (f32x4_t)(0.f);

    int wo = t >> 1, wq = t & 1;               // w2: 128 rows, 2 thr/row
    int hf = t >> 2, hq = t & 3;               // ht: 64 rows, 4 thr/row

    int kt0 = ks * 4;
    for (int kt = kt0; kt < kt0 + 4; ++kt) {
        int k0 = kt * 64;
        __syncthreads();
        // W: 128o x 64k fp32 -> bf16 (guard o>=125 -> 0), native casts
        {
            union { __bf16 h[32]; uint4 v[4]; } p;
            if (wo < OUT2_) {
                const float* src = w2 + (size_t)wo * K_ + k0 + wq * 32;
#pragma unroll
                for (int q = 0; q < 8; ++q) {
                    float4 v = *(const float4*)(src + q * 4);
                    p.h[q * 4]     = (__bf16)v.x;
                    p.h[q * 4 + 1] = (__bf16)v.y;
                    p.h[q * 4 + 2] = (__bf16)v.z;
                    p.h[q * 4 + 3] = (__bf16)v.w;
                }
            } else {
#pragma unroll
                for (int q = 0; q < 4; ++q) p.v[q] = make_uint4(0, 0, 0, 0);
            }
            uint4* d = (uint4*)&W_s[wo * 72 + wq * 32];
#pragma unroll
            for (int q = 0; q < 4; ++q) d[q] = p.v[q];
        }
        // H: 64f x 64k bf16 copy (2 uint4/thread)
        {
            const uint4* src = (const uint4*)(ht + ((size_t)b * F_ + f0 + hf) * K_ + k0) + hq * 2;
            uint4* d = (uint4*)&H_s[hf * 72 + hq * 16];
            d[0] = src[0]; d[1] = src[1];
        }
        __syncthreads();
#pragma unroll
        for (int kh = 0; kh < 2; ++kh) {
            bf16x8_t bf = *(const bf16x8_t*)&H_s[(wave * 16 + l15) * 72 + kh * 32 + quad * 8];
#pragma unroll
            for (int m = 0; m < 8; ++m) {
                bf16x8_t af = *(const bf16x8_t*)&W_s[(m * 16 + l15) * 72 + kh * 32 + quad * 8];
                acc[m] = __builtin_amdgcn_mfma_f32_16x16x32_bf16(af, bf, acc[m], 0, 0, 0);
            }
        }
    }
    // partials: part[((ks*32+b)*128 + f)*128 + o], f32x4 along o
    int f = f0 + wave * 16 + l15;
    float* prow = part + ((size_t)(ks * 32 + b) * 128 + f) * 128;
#pragma unroll
    for (int m = 0; m < 8; ++m)
        *(f32x4_t*)&prow[m * 16 + quad * 4] = acc[m];
}

// ---------------- out2 epilogue: out = relu(sum_s part + b2) -----------------
__global__ __launch_bounds__(256) void k_out2e(const float* __restrict__ part,
                                               const float* __restrict__ b2,
                                               float* __restrict__ out) {
    int idx = blockIdx.x * 256 + threadIdx.x;           // over B*F*OUT2 = 512000
    if (idx >= B_ * F_ * OUT2_) return;
    int o  = idx % OUT2_;
    int bf = idx / OUT2_;                               // b*F + f, in [0, 4096)
    float v = b2[o];
#pragma unroll
    for (int s = 0; s < 4; ++s) v += part[((size_t)s * 4096 + bf) * 128 + o];
    out[idx] = v > 0.f ? v : 0.f;
}

extern "C" void kernel_launch(void* const* d_in, const int* in_sizes, int n_in,
                              void* d_out, int out_size, void* d_ws, size_t ws_size,
                              hipStream_t stream) {
    const float* x      = (const float*)d_in[0];
    const float* lin_w  = (const float*)d_in[1];
    const float* lin_b  = (const float*)d_in[2];
    const float* a      = (const float*)d_in[3];
    const float* bias   = (const float*)d_in[4];
    const float* lin2_w = (const float*)d_in[5];
    const float* lin2_b = (const float*)d_in[6];

    float* out = (float*)d_out;
    float* h2  = out;                                  // B*F*OUT2
    float* att = out + (size_t)B_ * F_ * OUT2_;        // B*K*K

    // ws: 512 (unused, layout-preserving) | s1 32K | s2 32K | ht bf16 8MB |
    // xt bf16 8MB (reused as part). total 17,041,408 B == proven footprint.
    float* ws = (float*)d_ws;
    float* s1 = ws + 512;
    float* s2 = ws + 512 + B_ * K_;
    unsigned short* ht = (unsigned short*)(ws + 512 + 2 * B_ * K_);   // B*F*K bf16
    unsigned short* xt = ht + (size_t)B_ * K_ * F_;                   // B*K*F bf16
    float* part = (float*)xt;   // 4*32*128*128 floats = 8 MB; xt dead after k_attx

    k_xts<<<dim3(16, B_), 256, 0, stream>>>(x, lin_w, lin_b, a, xt, s1, s2);
    k_attx<<<dim3(K_ / 32, B_), 256, 0, stream>>>(s1, s2, bias, xt, x, att, ht);
    k_out2m<<<dim3(2, B_, 4), 256, 0, stream>>>(ht, lin2_w, part);
    k_out2e<<<(B_ * F_ * OUT2_ + 255) / 256, 256, 0, stream>>>(part, lin2_b, h2);
}

// Round 8
// 279.672 us; speedup vs baseline: 1.1583x; 1.1583x over previous
//
#include <hip/hip_runtime.h>

#define B_ 32
#define K_ 1024
#define F_ 128
#define E_ 128
#define OUT2_ 125
#define ALPHA_ 0.2f

typedef __bf16 bf16x8_t __attribute__((ext_vector_type(8)));
typedef float  f32x4_t  __attribute__((ext_vector_type(4)));

// ------- x transpose+cvt + scores + (fused) prep ----------------------------
__global__ __launch_bounds__(256) void k_xts(const float* __restrict__ x,
                                             const float* __restrict__ lin_w,
                                             const float* __restrict__ lin_b,
                                             const float* __restrict__ a,
                                             unsigned short* __restrict__ xt,
                                             float* __restrict__ s1,
                                             float* __restrict__ s2) {
    int kt = blockIdx.x;
    int b  = blockIdx.y;
    int t  = threadIdx.x;
    __shared__ float xs[64 * 132];
    __shared__ float red1[4][64], red2[4][64];
    __shared__ float wsl[260];

    // ws: waves 0-1 -> a1 path (f = t), waves 2-3 -> a2 path
    {
        int f = t & 127, sel = t >> 7;
        const float* av = a + sel * 128;
        float acc = 0.f;
#pragma unroll 8
        for (int e = 0; e < E_; ++e) acc += lin_w[e * F_ + f] * av[e];
        wsl[sel * 128 + f] = acc;
        if (t < 2) {
            const float* aw = a + t * 128;
            float c = 0.f;
#pragma unroll 8
            for (int e = 0; e < E_; ++e) c += lin_b[e] * aw[e];
            wsl[256 + t] = c;
        }
    }
    const float* xb = x + ((size_t)b * K_ + kt * 64) * F_;
#pragma unroll
    for (int q = 0; q < 8; ++q) {
        int flat = q * 256 + t;
        int kk = flat >> 5, f4 = flat & 31;
        float4 v = *(const float4*)(xb + (size_t)kk * F_ + f4 * 4);
        xs[kk * 132 + f4 * 4]     = v.x;
        xs[kk * 132 + f4 * 4 + 1] = v.y;
        xs[kk * 132 + f4 * 4 + 2] = v.z;
        xs[kk * 132 + f4 * 4 + 3] = v.w;
    }
    __syncthreads();
    // transpose-pack (bf16) — native casts
    {
        int f = t >> 1, half = t & 1;
        union { __bf16 h[32]; uint4 v[4]; } pack;
#pragma unroll
        for (int i = 0; i < 32; ++i) pack.h[i] = (__bf16)xs[(half * 32 + i) * 132 + f];
        unsigned short* dst = xt + (((size_t)(b * 16 + kt) * 128 + f) * 64 + half * 32);
        uint4* d4 = (uint4*)dst;
#pragma unroll
        for (int i = 0; i < 4; ++i) d4[i] = pack.v[i];
    }
    // scores: row r = t&63, f-segment p = t>>6 (32 f each), reduce via LDS
    {
        int r = t & 63, p = t >> 6;
        const float4* xr = (const float4*)&xs[r * 132 + p * 32];
        const float4* w1 = (const float4*)&wsl[p * 32];
        const float4* w2 = (const float4*)&wsl[128 + p * 32];
        float a1 = 0.f, a2 = 0.f;
#pragma unroll
        for (int q = 0; q < 8; ++q) {
            float4 xv = xr[q];
            float4 wa = w1[q], wb = w2[q];
            a1 += xv.x * wa.x + xv.y * wa.y + xv.z * wa.z + xv.w * wa.w;
            a2 += xv.x * wb.x + xv.y * wb.y + xv.z * wb.z + xv.w * wb.w;
        }
        red1[p][r] = a1; red2[p][r] = a2;
    }
    __syncthreads();
    if (t < 64) {
        s1[(size_t)b * K_ + kt * 64 + t] =
            red1[0][t] + red1[1][t] + red1[2][t] + red1[3][t] + wsl[256];
    } else if (t < 128) {
        int r = t - 64;
        s2[(size_t)b * K_ + kt * 64 + r] =
            red2[0][r] + red2[1][r] + red2[2][r] + red2[3][r] + wsl[257];
    }
}

// ---------------- softmax: one block per (i,b) row, no max pass --------------
// Streaming att writer. Round-7 lesson: fusing this write into the consumer
// is wrong — 16MB/XCD of fresh writes vs 4MB L2 means the "local readback"
// becomes an HBM round trip serialized within each block. Keep it standalone.
__global__ __launch_bounds__(256) void k_softmax(const float* __restrict__ s1,
                                                 const float* __restrict__ s2,
                                                 const float* __restrict__ bias,
                                                 float* __restrict__ att) {
    int i = blockIdx.x >> 5;
    int b = blockIdx.x & 31;
    int t = threadIdx.x;
    float sv = s1[b * K_ + i];
    float4 s2v = ((const float4*)(s2 + b * K_))[t];
    float4 bv  = ((const float4*)(bias + (size_t)i * K_))[t];
    float e[4];
    {
        float v;
        v = sv + s2v.x; v = v > 0.f ? v : ALPHA_ * v; e[0] = __expf(v + bv.x);
        v = sv + s2v.y; v = v > 0.f ? v : ALPHA_ * v; e[1] = __expf(v + bv.y);
        v = sv + s2v.z; v = v > 0.f ? v : ALPHA_ * v; e[2] = __expf(v + bv.z);
        v = sv + s2v.w; v = v > 0.f ? v : ALPHA_ * v; e[3] = __expf(v + bv.w);
    }
    float sum = e[0] + e[1] + e[2] + e[3];
    for (int m = 32; m; m >>= 1) sum += __shfl_xor(sum, m, 64);
    __shared__ float reds[4];
    int wave = t >> 6, lane = t & 63;
    if (lane == 0) reds[wave] = sum;
    __syncthreads();
    sum = reds[0] + reds[1] + reds[2] + reds[3];
    float r = 1.f / sum;
    float4 o; o.x = e[0] * r; o.y = e[1] * r; o.z = e[2] * r; o.w = e[3] * r;
    ((float4*)(att + ((size_t)b * K_ + i) * K_))[t] = o;
}

// ---------------- att@x via bf16 MFMA: 32i x 128f, dbuf X, pipelined A -------
// Round-6 structure + round-8 XCD-chunked swizzle (T1): 1024%8==0, bijective.
// Each XCD owns 4 consecutive b values -> its xt working set (4 x 256KB =
// 1MB) stays L2-resident across the 32 i-blocks that re-read it; att is
// streamed-once so it loses nothing.
__global__ __launch_bounds__(256, 4) void k_attx(const float* __restrict__ att,
                                                 const unsigned short* __restrict__ xt,
                                                 const float* __restrict__ x,
                                                 unsigned short* __restrict__ ht) {
    int flatb = blockIdx.y * gridDim.x + blockIdx.x;     // [0,1024)
    int swz   = (flatb & 7) * 128 + (flatb >> 3);        // XCD-chunked, bijective
    int b  = swz >> 5;
    int i0 = (swz & 31) * 32;
    int t  = threadIdx.x;
    int wave = t >> 6, lane = t & 63;
    int quad = lane >> 4, l15 = lane & 15;

    __shared__ unsigned short X_s[2][128 * 64];   // swizzled, double-buffered

    const float* ab  = att + ((size_t)b * K_ + i0) * K_;
    const uint4* xtb = (const uint4*)(xt + (size_t)b * 16 * 128 * 64);

    const float* arow[2];
    arow[0] = ab + (size_t)l15 * K_ + quad * 8;
    arow[1] = arow[0] + 16 * K_;

    f32x4_t acc[2][2];
#pragma unroll
    for (int m = 0; m < 2; ++m)
#pragma unroll
        for (int n = 0; n < 2; ++n) acc[m][n] = (f32x4_t)(0.f);

    bf16x8_t afc[2][2];
    // prologue: issue A0 loads, stage X0 into buf 0, cvt A0
    {
        float4 av[2][2][2];
#pragma unroll
        for (int m = 0; m < 2; ++m)
#pragma unroll
            for (int kh = 0; kh < 2; ++kh) {
                av[m][kh][0] = *(const float4*)(arow[m] + kh * 32);
                av[m][kh][1] = *(const float4*)(arow[m] + kh * 32 + 4);
            }
#pragma unroll
        for (int q = 0; q < 4; ++q) {
            int flat2 = q * 256 + t;
            int row = flat2 >> 3, g = flat2 & 7;
            *(uint4*)&X_s[0][row * 64 + 8 * (g ^ (row & 7))] = xtb[flat2];
        }
#pragma unroll
        for (int m = 0; m < 2; ++m)
#pragma unroll
            for (int kh = 0; kh < 2; ++kh) {
                union { __bf16 h[8]; bf16x8_t v; } p;
                float4 v0 = av[m][kh][0], v1 = av[m][kh][1];
                p.h[0] = (__bf16)v0.x; p.h[1] = (__bf16)v0.y;
                p.h[2] = (__bf16)v0.z; p.h[3] = (__bf16)v0.w;
                p.h[4] = (__bf16)v1.x; p.h[5] = (__bf16)v1.y;
                p.h[6] = (__bf16)v1.z; p.h[7] = (__bf16)v1.w;
                afc[m][kh] = p.v;
            }
    }
    __syncthreads();

    int cur = 0;
#pragma unroll
    for (int kt = 0; kt < 16; ++kt) {
        uint4 xn[4];
        float4 av[2][2][2];
        if (kt < 15) {
            // issue next X + next A loads (consumed after the MFMAs below)
            const uint4* src = xtb + (size_t)(kt + 1) * 1024;
#pragma unroll
            for (int q = 0; q < 4; ++q) xn[q] = src[q * 256 + t];
            int ko = (kt + 1) * 64;
#pragma unroll
            for (int m = 0; m < 2; ++m)
#pragma unroll
                for (int kh = 0; kh < 2; ++kh) {
                    av[m][kh][0] = *(const float4*)(arow[m] + ko + kh * 32);
                    av[m][kh][1] = *(const float4*)(arow[m] + ko + kh * 32 + 4);
                }
        }
        // MFMAs for tile kt from afc + X_s[cur]
#pragma unroll
        for (int kh = 0; kh < 2; ++kh) {
            bf16x8_t bff[2];
#pragma unroll
            for (int n = 0; n < 2; ++n) {
                int row = wave * 32 + n * 16 + l15;
                bff[n] = *(const bf16x8_t*)&X_s[cur][row * 64 + 8 * (((kh << 2) | quad) ^ (row & 7))];
            }
#pragma unroll
            for (int m = 0; m < 2; ++m)
#pragma unroll
                for (int n = 0; n < 2; ++n)
                    acc[m][n] = __builtin_amdgcn_mfma_f32_16x16x32_bf16(afc[m][kh], bff[n], acc[m][n], 0, 0, 0);
        }
        if (kt < 15) {
            // cvt next A into afc (after MFMA issue — latency hidden)
#pragma unroll
            for (int m = 0; m < 2; ++m)
#pragma unroll
                for (int kh = 0; kh < 2; ++kh) {
                    union { __bf16 h[8]; bf16x8_t v; } p;
                    float4 v0 = av[m][kh][0], v1 = av[m][kh][1];
                    p.h[0] = (__bf16)v0.x; p.h[1] = (__bf16)v0.y;
                    p.h[2] = (__bf16)v0.z; p.h[3] = (__bf16)v0.w;
                    p.h[4] = (__bf16)v1.x; p.h[5] = (__bf16)v1.y;
                    p.h[6] = (__bf16)v1.z; p.h[7] = (__bf16)v1.w;
                    afc[m][kh] = p.v;
                }
            // stage next X into buf[cur^1]
#pragma unroll
            for (int q = 0; q < 4; ++q) {
                int flat2 = q * 256 + t;
                int row = flat2 >> 3, g = flat2 & 7;
                *(uint4*)&X_s[cur ^ 1][row * 64 + 8 * (g ^ (row & 7))] = xn[q];
            }
        }
        __syncthreads();
        cur ^= 1;
    }
    // epilogue: ht[b][f][i] = bf16(acc + x residual), 8B packed along i
#pragma unroll
    for (int m = 0; m < 2; ++m) {
#pragma unroll
        for (int n = 0; n < 2; ++n) {
            int f = wave * 32 + n * 16 + l15;
            int ib = i0 + m * 16 + quad * 4;
            union { __bf16 h[4]; ushort4 v; } p;
#pragma unroll
            for (int r = 0; r < 4; ++r) {
                int i = ib + r;
                p.h[r] = (__bf16)(acc[m][n][r] + x[((size_t)b * K_ + i) * F_ + f]);
            }
            *(ushort4*)&ht[((size_t)b * F_ + f) * K_ + ib] = p.v;
        }
    }
}

// ---------------- out2 MFMA split-K: per (fh,b,ks): C[o128][f64], K=256 ------
__global__ __launch_bounds__(256) void k_out2m(const unsigned short* __restrict__ ht,
                                               const float* __restrict__ w2,
                                               float* __restrict__ part) {
    int b  = blockIdx.y;
    int f0 = blockIdx.x * 64;
    int ks = blockIdx.z;
    int t  = threadIdx.x;
    int wave = t >> 6, lane = t & 63;
    int quad = lane >> 4, l15 = lane & 15;

    __shared__ unsigned short W_s[128 * 72];   // 128o x 64k
    __shared__ unsigned short H_s[64 * 72];    // 64f  x 64k

    f32x4_t acc[8];
#pragma unroll
    for (int m = 0; m < 8; ++m) acc[m] = (f32x4_t)(0.f);

    int wo = t >> 1, wq = t & 1;               // w2: 128 rows, 2 thr/row
    int hf = t >> 2, hq = t & 3;               // ht: 64 rows, 4 thr/row

    int kt0 = ks * 4;
    for (int kt = kt0; kt < kt0 + 4; ++kt) {
        int k0 = kt * 64;
        __syncthreads();
        // W: 128o x 64k fp32 -> bf16 (guard o>=125 -> 0), native casts
        {
            union { __bf16 h[32]; uint4 v[4]; } p;
            if (wo < OUT2_) {
                const float* src = w2 + (size_t)wo * K_ + k0 + wq * 32;
#pragma unroll
                for (int q = 0; q < 8; ++q) {
                    float4 v = *(const float4*)(src + q * 4);
                    p.h[q * 4]     = (__bf16)v.x;
                    p.h[q * 4 + 1] = (__bf16)v.y;
                    p.h[q * 4 + 2] = (__bf16)v.z;
                    p.h[q * 4 + 3] = (__bf16)v.w;
                }
            } else {
#pragma unroll
                for (int q = 0; q < 4; ++q) p.v[q] = make_uint4(0, 0, 0, 0);
            }
            uint4* d = (uint4*)&W_s[wo * 72 + wq * 32];
#pragma unroll
            for (int q = 0; q < 4; ++q) d[q] = p.v[q];
        }
        // H: 64f x 64k bf16 copy (2 uint4/thread)
        {
            const uint4* src = (const uint4*)(ht + ((size_t)b * F_ + f0 + hf) * K_ + k0) + hq * 2;
            uint4* d = (uint4*)&H_s[hf * 72 + hq * 16];
            d[0] = src[0]; d[1] = src[1];
        }
        __syncthreads();
#pragma unroll
        for (int kh = 0; kh < 2; ++kh) {
            bf16x8_t bf = *(const bf16x8_t*)&H_s[(wave * 16 + l15) * 72 + kh * 32 + quad * 8];
#pragma unroll
            for (int m = 0; m < 8; ++m) {
                bf16x8_t af = *(const bf16x8_t*)&W_s[(m * 16 + l15) * 72 + kh * 32 + quad * 8];
                acc[m] = __builtin_amdgcn_mfma_f32_16x16x32_bf16(af, bf, acc[m], 0, 0, 0);
            }
        }
    }
    // partials: part[((ks*32+b)*128 + f)*128 + o], f32x4 along o
    int f = f0 + wave * 16 + l15;
    float* prow = part + ((size_t)(ks * 32 + b) * 128 + f) * 128;
#pragma unroll
    for (int m = 0; m < 8; ++m)
        *(f32x4_t*)&prow[m * 16 + quad * 4] = acc[m];
}

// ---------------- out2 epilogue: out = relu(sum_s part + b2) -----------------
__global__ __launch_bounds__(256) void k_out2e(const float* __restrict__ part,
                                               const float* __restrict__ b2,
                                               float* __restrict__ out) {
    int idx = blockIdx.x * 256 + threadIdx.x;           // over B*F*OUT2 = 512000
    if (idx >= B_ * F_ * OUT2_) return;
    int o  = idx % OUT2_;
    int bf = idx / OUT2_;                               // b*F + f, in [0, 4096)
    float v = b2[o];
#pragma unroll
    for (int s = 0; s < 4; ++s) v += part[((size_t)s * 4096 + bf) * 128 + o];
    out[idx] = v > 0.f ? v : 0.f;
}

extern "C" void kernel_launch(void* const* d_in, const int* in_sizes, int n_in,
                              void* d_out, int out_size, void* d_ws, size_t ws_size,
                              hipStream_t stream) {
    const float* x      = (const float*)d_in[0];
    const float* lin_w  = (const float*)d_in[1];
    const float* lin_b  = (const float*)d_in[2];
    const float* a      = (const float*)d_in[3];
    const float* bias   = (const float*)d_in[4];
    const float* lin2_w = (const float*)d_in[5];
    const float* lin2_b = (const float*)d_in[6];

    float* out = (float*)d_out;
    float* h2  = out;                                  // B*F*OUT2
    float* att = out + (size_t)B_ * F_ * OUT2_;        // B*K*K

    // ws: 512 (unused, layout-preserving) | s1 32K | s2 32K | ht bf16 8MB |
    // xt bf16 8MB (reused as part). total 17,041,408 B == proven footprint.
    float* ws = (float*)d_ws;
    float* s1 = ws + 512;
    float* s2 = ws + 512 + B_ * K_;
    unsigned short* ht = (unsigned short*)(ws + 512 + 2 * B_ * K_);   // B*F*K bf16
    unsigned short* xt = ht + (size_t)B_ * K_ * F_;                   // B*K*F bf16
    float* part = (float*)xt;   // 4*32*128*128 floats = 8 MB; xt dead after k_attx

    k_xts<<<dim3(16, B_), 256, 0, stream>>>(x, lin_w, lin_b, a, xt, s1, s2);
    k_softmax<<<B_ * K_, 256, 0, stream>>>(s1, s2, bias, att);
    k_attx<<<dim3(K_ / 32, B_), 256, 0, stream>>>(att, xt, x, ht);
    k_out2m<<<dim3(2, B_, 4), 256, 0, stream>>>(ht, lin2_w, part);
    k_out2e<<<(B_ * F_ * OUT2_ + 255) / 256, 256, 0, stream>>>(part, lin2_b, h2);
}